// Round 7
// baseline (378.066 us; speedup 1.0000x reference)
//
#include <hip/hip_runtime.h>

typedef float floatx4 __attribute__((ext_vector_type(4)));
typedef __bf16 bf16x8 __attribute__((ext_vector_type(8)));
using u16 = unsigned short;
using u32 = unsigned int;

#define GLOBAL_AS __attribute__((address_space(1)))
#define LDS_AS    __attribute__((address_space(3)))

// ---------------- conversion: x fp32 -> bf16 (RNE) ----------------
__global__ void cvt_x_kernel(const float* __restrict__ x, u16* __restrict__ xb, int n8) {
  int stride = gridDim.x * blockDim.x;
  for (int i = blockIdx.x * blockDim.x + threadIdx.x; i < n8; i += stride) {
    const float4* p = (const float4*)(x + (size_t)i * 8);
    float4 a = p[0], b = p[1];
    float v[8] = {a.x, a.y, a.z, a.w, b.x, b.y, b.z, b.w};
    u32 r[8];
#pragma unroll
    for (int j = 0; j < 8; ++j) {
      u32 u = __float_as_uint(v[j]);
      r[j] = (u + 0x7FFFu + ((u >> 16) & 1u)) >> 16;  // RNE
    }
    uint4 o;
    o.x = r[0] | (r[1] << 16);
    o.y = r[2] | (r[3] << 16);
    o.z = r[4] | (r[5] << 16);
    o.w = r[6] | (r[7] << 16);
    *(uint4*)(xb + (size_t)i * 8) = o;
  }
}

// ------- quantize W -> 2-bit ternary codes, fragment-ordered + reader-coalesced -------
// Code c = nz | sg<<1 (c in {0,1,3}); 8 codes (e=0..7, k-consecutive) per u16 at bits 2e.
// Per (panel=n>>8, tile=k>>6): 2048 u16. Group (wf,l): wf = (f>>2)*16 + wc*4 + (f&3),
// f = ng*2 + j, l = g*16 + r  [n = panel*256 + wc*64 + ng*16 + r; k = tile*64 + j*32 + g*8 + e].
// Storage index (coalesced for the GEMM reader): idx = (wf>>2)*256 + l*4 + (wf&3).
__global__ void quant_w_pack(const float* __restrict__ w, u16* __restrict__ wb,
                             int K, int Kd8, int n8) {
  int stride = gridDim.x * blockDim.x;
  for (int i = blockIdx.x * blockDim.x + threadIdx.x; i < n8; i += stride) {
    const int n = i / Kd8;
    const int k = (i - n * Kd8) * 8;
    const float4* p = (const float4*)(w + (size_t)n * K + k);
    float4 a = p[0], b = p[1];
    float v[8] = {a.x, a.y, a.z, a.w, b.x, b.y, b.z, b.w};
    u32 pk = 0;
#pragma unroll
    for (int e = 0; e < 8; ++e) {
      u32 c = (v[e] > 0.05f) ? 1u : ((v[e] < -0.05f) ? 3u : 0u);
      pk |= c << (2 * e);
    }
    const int panel = n >> 8, nl = n & 255;
    const int wc = nl >> 6, ng = (nl >> 4) & 3, r = nl & 15;
    const int tile = k >> 6, j = (k >> 5) & 1, g = (k >> 3) & 3;
    const int f = ng * 2 + j, l = g * 16 + r;
    const int wf = ((f >> 2) << 4) + (wc << 2) + (f & 3);
    const int idx = ((wf >> 2) << 8) + (l << 2) + (wf & 3);
    wb[(size_t)panel * (K >> 6) * 2048 + tile * 2048 + idx] = (u16)pk;
  }
}

// ---------------- 256x256 BK=64 4-phase bf16 GEMM; A via gload_lds, B 2-bit+decode ----------------
// Round-5 m201 skeleton (phases/barriers/MFMA/epilogue identical). Changes:
// B staged by: plain-load 8B/thread packed codes (lead 2 tiles, ping-pong regs) ->
// VALU decode d(c)=c*0x3F80+((c>>1)<<8) -> 4 lane-sequential ds_write_b128 (P2).
// Manual waits: end-P2 vmcnt(3) (drains A_hi(t), keeps {pk,A_lo'}), end-P4 vmcnt(2)
// (drains pk+A_lo', keeps A_hi') -- robust to compiler load-order within a phase.
__global__ __launch_bounds__(512, 2) void gemm_bin_pk(
    const u16* __restrict__ A, const u16* __restrict__ Bp,
    const float* __restrict__ bias, float* __restrict__ C,
    int M, int N, int K) {
  __shared__ u16 lds[65536];  // 128 KiB: 2 buf x (A 16384 | B 16384) u16

  const int tid = threadIdx.x;
  const int w = tid >> 6, l = tid & 63;
  const int wr = w >> 2, wc = w & 3;
  const int r = l & 15;

  const int nbn = N >> 8;
  int wg = blockIdx.x;
  const int nwg = gridDim.x;
  if ((nwg & 7) == 0) wg = (wg & 7) * (nwg >> 3) + (wg >> 3);  // XCD swizzle (bijective)
  const int bm = wg / nbn, bn = wg % nbn;

  const int T = K >> 6;

  // A staging source (fragment-permuted; round-5-verified)
  const int srow = ((tid >> 7) << 4) + (tid & 15);
  const int skk = (((tid >> 6) & 1) << 5) + (((tid >> 4) & 3) << 3);
  const size_t aLo0 = (size_t)(bm * 256 + srow) * K + skk;
  const size_t cs = (size_t)128 * K;

  // packed-B per-thread source: uint2 per tile
  const u16* const pkp = Bp + (size_t)bn * (K >> 6) * 2048 + ((tid >> 6) << 8) + ((tid & 63) << 2);
  // decode LDS dest (u16 offset within buffer): 16384 + wf*512 + l*8, wf = (tid>>6)*4+q
  const int bdst = 16384 + ((tid >> 6) << 11) + ((tid & 63) << 3);

  const u16* const afp0 = lds + wr * 8192 + l * 8;
  const u16* const bfp0 = lds + 16384 + wc * 2048 + l * 8;

  floatx4 acc[8][4] = {};
  bf16x8 af[8], bflo[4], bfhi[4];
  uint2 pkA, pkB;

#define GLOAD(gptr, u16off)                                                    \
  __builtin_amdgcn_global_load_lds((const GLOBAL_AS void*)(gptr),              \
                                   (LDS_AS void*)(lds + (u16off)), 16, 0, 0)
#define BARRIER __builtin_amdgcn_s_barrier()
#define LGKM0  do { asm volatile("s_waitcnt lgkmcnt(0)" ::: "memory");         \
                    __builtin_amdgcn_sched_barrier(0); } while (0)

#define DECODE(PK, bufn_)                                                      \
  {                                                                            \
    _Pragma("unroll")                                                          \
    for (int q = 0; q < 4; ++q) {                                              \
      u32 word = (q < 2) ? PK.x : PK.y;                                        \
      u32 vv = (q & 1) ? (word >> 16) : (word & 0xFFFFu);                      \
      u32 o[4];                                                                \
      _Pragma("unroll")                                                        \
      for (int ii = 0; ii < 4; ++ii) {                                         \
        u32 x = (vv >> (4 * ii)) & 0xFu;                                       \
        u32 c0 = x & 3u, c1 = x >> 2;                                          \
        u32 lo = c0 * 0x3F80u + ((c0 >> 1) << 8);                              \
        u32 hi = c1 * 0x3F80u + ((c1 >> 1) << 8);                              \
        o[ii] = lo | (hi << 16);                                               \
      }                                                                        \
      uint4 ov; ov.x = o[0]; ov.y = o[1]; ov.z = o[2]; ov.w = o[3];            \
      *(uint4*)(lds + (bufn_) + bdst + q * 512) = ov;                          \
    }                                                                          \
  }

  // ---- prologue: pk(0),pk(1); stage A(0); decode B(0) -> buf0; drain ----
  pkA = *(const uint2*)(pkp);           // pk(0)
  pkB = *(const uint2*)(pkp + 2048);    // pk(1)
  GLOAD(A + aLo0,                    0 + tid * 8);
  GLOAD(A + aLo0 + cs,            8192 + tid * 8);
  GLOAD(A + aLo0 + (size_t)64 * K,        4096 + tid * 8);
  GLOAD(A + aLo0 + (size_t)64 * K + cs,  12288 + tid * 8);
  DECODE(pkA, 0)
  asm volatile("s_waitcnt vmcnt(0)" ::: "memory");
  asm volatile("s_waitcnt lgkmcnt(0)" ::: "memory");
  BARRIER;

#define TILE(t, PKC, PKN)                                                      \
  {                                                                            \
    const int bufc = ((t) & 1) << 15;                                          \
    const int bufn = bufc ^ 32768;                                             \
    const bool doSt = (t) + 1 < T;                                             \
    const bool doPk = (t) + 2 < T;                                             \
    const size_t kadv = (size_t)((t) + 1) << 6;                                \
    const u16* afp = afp0 + bufc;                                              \
    const u16* bfp = bfp0 + bufc;                                              \
    /* ---- P1: af m0 (8) + bflo (4); load pk(t+2); stage A_lo' ---- */        \
    if (doPk) PKN = *(const uint2*)(pkp + (size_t)((t) + 2) * 2048);           \
    _Pragma("unroll")                                                          \
    for (int i = 0; i < 8; ++i) af[i] = *(const bf16x8*)(afp + i * 512);       \
    _Pragma("unroll")                                                          \
    for (int i = 0; i < 4; ++i) bflo[i] = *(const bf16x8*)(bfp + i * 512);     \
    if (doSt) {                                                                \
      GLOAD(A + aLo0 + kadv,      bufn + 0 + tid * 8);                         \
      GLOAD(A + aLo0 + cs + kadv, bufn + 8192 + tid * 8);                      \
    }                                                                          \
    asm volatile("s_waitcnt lgkmcnt(8)" ::: "memory");                         \
    BARRIER;                                                                   \
    LGKM0;                                                                     \
    __builtin_amdgcn_s_setprio(1);                                             \
    _Pragma("unroll")                                                          \
    for (int j = 0; j < 2; ++j)                                                \
      _Pragma("unroll")                                                        \
      for (int mg = 0; mg < 4; ++mg)                                           \
        _Pragma("unroll")                                                      \
        for (int ng = 0; ng < 2; ++ng)                                         \
          acc[mg][ng] = __builtin_amdgcn_mfma_f32_16x16x32_bf16(               \
              af[mg * 2 + j], bflo[ng * 2 + j], acc[mg][ng], 0, 0, 0);         \
    __builtin_amdgcn_s_setprio(0);                                             \
    BARRIER;                                                                   \
    /* ---- P2: bfhi (4); decode B(t+1) -> bufn; Q(m0,n23) ---- */             \
    _Pragma("unroll")                                                          \
    for (int i = 0; i < 4; ++i) bfhi[i] = *(const bf16x8*)(bfp + 8192 + i * 512); \
    if (doSt) DECODE(PKC, bufn)                                                \
    BARRIER;                                                                   \
    LGKM0;                                                                     \
    __builtin_amdgcn_s_setprio(1);                                             \
    _Pragma("unroll")                                                          \
    for (int j = 0; j < 2; ++j)                                                \
      _Pragma("unroll")                                                        \
      for (int mg = 0; mg < 4; ++mg)                                           \
        _Pragma("unroll")                                                      \
        for (int ng = 0; ng < 2; ++ng)                                         \
          acc[mg][2 + ng] = __builtin_amdgcn_mfma_f32_16x16x32_bf16(           \
              af[mg * 2 + j], bfhi[ng * 2 + j], acc[mg][2 + ng], 0, 0, 0);     \
    __builtin_amdgcn_s_setprio(0);                                             \
    if (doPk) asm volatile("s_waitcnt vmcnt(3)" ::: "memory");                 \
    else      asm volatile("s_waitcnt vmcnt(0)" ::: "memory");                 \
    BARRIER;                                                                   \
    /* ---- P3: af m1 (8); Q(m1,n01) ---- */                                   \
    _Pragma("unroll")                                                          \
    for (int i = 0; i < 8; ++i) af[i] = *(const bf16x8*)(afp + 4096 + i * 512); \
    asm volatile("s_waitcnt lgkmcnt(4)" ::: "memory");                         \
    BARRIER;                                                                   \
    LGKM0;                                                                     \
    __builtin_amdgcn_s_setprio(1);                                             \
    _Pragma("unroll")                                                          \
    for (int j = 0; j < 2; ++j)                                                \
      _Pragma("unroll")                                                        \
      for (int mg = 0; mg < 4; ++mg)                                           \
        _Pragma("unroll")                                                      \
        for (int ng = 0; ng < 2; ++ng)                                         \
          acc[4 + mg][ng] = __builtin_amdgcn_mfma_f32_16x16x32_bf16(           \
              af[mg * 2 + j], bflo[ng * 2 + j], acc[4 + mg][ng], 0, 0, 0);     \
    __builtin_amdgcn_s_setprio(0);                                             \
    BARRIER;                                                                   \
    /* ---- P4: stage A_hi'; Q(m1,n23) ---- */                                 \
    if (doSt) {                                                                \
      GLOAD(A + aLo0 + (size_t)64 * K + kadv,      bufn + 4096 + tid * 8);     \
      GLOAD(A + aLo0 + (size_t)64 * K + cs + kadv, bufn + 12288 + tid * 8);    \
    }                                                                          \
    BARRIER;                                                                   \
    __builtin_amdgcn_s_setprio(1);                                             \
    _Pragma("unroll")                                                          \
    for (int j = 0; j < 2; ++j)                                                \
      _Pragma("unroll")                                                        \
      for (int mg = 0; mg < 4; ++mg)                                           \
        _Pragma("unroll")                                                      \
        for (int ng = 0; ng < 2; ++ng)                                         \
          acc[4 + mg][2 + ng] = __builtin_amdgcn_mfma_f32_16x16x32_bf16(       \
              af[mg * 2 + j], bfhi[ng * 2 + j], acc[4 + mg][2 + ng], 0, 0, 0); \
    __builtin_amdgcn_s_setprio(0);                                             \
    if (doPk) asm volatile("s_waitcnt vmcnt(2)" ::: "memory");                 \
    else      asm volatile("s_waitcnt vmcnt(0)" ::: "memory");                 \
    BARRIER;                                                                   \
  }

  for (int tt = 0; tt < T; tt += 2) {
    TILE(tt,     pkB, pkA)   // entering even t: pkB holds pk(t+1), load pk(t+2)->pkA
    TILE(tt + 1, pkA, pkB)
  }
#undef TILE
#undef DECODE
#undef GLOAD
#undef BARRIER
#undef LGKM0

  // ---- epilogue: C/D layout col = l&15, row = (l>>4)*4 + q ----
  const int g = l >> 4;
  const int colb = bn * 256 + wc * 64;
  float bv[4];
#pragma unroll
  for (int n = 0; n < 4; ++n) bv[n] = bias[colb + n * 16 + r];
  const int rowb0 = bm * 256 + wr * 128;
#pragma unroll
  for (int m = 0; m < 8; ++m) {
    const int rowb = rowb0 + m * 16 + g * 4;
#pragma unroll
    for (int n = 0; n < 4; ++n) {
      const int col = colb + n * 16 + r;
      float* cp = C + (size_t)rowb * N + col;
#pragma unroll
      for (int q = 0; q < 4; ++q) cp[(size_t)q * N] = acc[m][n][q] + bv[n];
    }
  }
}

// ---------------- fallback: slow but correct ----------------
__global__ void gemm_naive_kernel(const float* __restrict__ x, const float* __restrict__ wgt,
                                  const float* __restrict__ bias, float* __restrict__ out,
                                  int M, int N, int K) {
  long long idx = (long long)blockIdx.x * blockDim.x + threadIdx.x;
  if (idx >= (long long)M * N) return;
  int o = (int)(idx % N);
  int m = (int)(idx / N);
  const float* xr = x + (size_t)m * K;
  const float* wr = wgt + (size_t)o * K;
  float s = 0.f;
  for (int i = 0; i < K; ++i) {
    float wv = wr[i];
    float t = (wv > 0.05f) ? 1.f : ((wv < -0.05f) ? -1.f : 0.f);
    s = fmaf(xr[i], t, s);
  }
  out[idx] = s + bias[o];
}

extern "C" void kernel_launch(void* const* d_in, const int* in_sizes, int n_in,
                              void* d_out, int out_size, void* d_ws, size_t ws_size,
                              hipStream_t stream) {
  const float* x    = (const float*)d_in[0];
  const float* wgt  = (const float*)d_in[1];
  const float* bias = (const float*)d_in[2];
  float* out = (float*)d_out;

  const int N = in_sizes[2];                 // out features
  const int K = in_sizes[1] / N;             // in features
  const int M = in_sizes[0] / K;             // batch rows

  const size_t need = (size_t)M * K * 2 + (size_t)N * K / 4;  // bf16 A + 2-bit B
  if (ws_size >= need && (M % 256 == 0) && (N % 256 == 0) && (K % 128 == 0) && K >= 256) {
    u16* xb = (u16*)d_ws;
    u16* wb = xb + (size_t)M * K;
    const int nx8 = (M * K) / 8;
    const int nw8 = (N * K) / 8;
    cvt_x_kernel<<<2048, 256, 0, stream>>>(x, xb, nx8);
    quant_w_pack<<<2048, 256, 0, stream>>>(wgt, wb, K, K / 8, nw8);
    const int grid = (M / 256) * (N / 256);
    gemm_bin_pk<<<grid, 512, 0, stream>>>(xb, wb, bias, out, M, N, K);
  } else {
    const long long total = (long long)M * N;
    gemm_naive_kernel<<<(unsigned)((total + 255) / 256), 256, 0, stream>>>(x, wgt, bias, out, M, N, K);
  }
}